// Round 11
// baseline (258.401 us; speedup 1.0000x reference)
//
#include <hip/hip_runtime.h>
#include <math.h>

#define B_ 2
#define H_ 16
#define S_ 2048
#define CTX_ 1024
#define VD_ 288
#define VD2_ 576
#define FFN_ 512
#define FFNH_ 256
#define NH1_ 17
#define EPSILON_ 0.066f
#define LN_EPS_ 1e-5f
#define TPB_ 8                    // tokens per block
#define NBLK_ (B_ * S_ / TPB_)    // 512 blocks -> 2 blocks/CU

typedef float vfloat4 __attribute__((ext_vector_type(4)));

__device__ __forceinline__ float gelu_exact(float x) {
    return 0.5f * x * (1.0f + erff(x * 0.70710678118654752440f));
}
__device__ __forceinline__ vfloat4 gelu4(vfloat4 v) {
    vfloat4 o;
    o.x = gelu_exact(v.x); o.y = gelu_exact(v.y);
    o.z = gelu_exact(v.z); o.w = gelu_exact(v.w);
    return o;
}

// one-block fused histogram (proven round 4)
__global__ __launch_bounds__(1024) void count_kernel(
    const int* __restrict__ ids, int* __restrict__ counts)
{
    __shared__ int hist[CTX_];
    const int t = threadIdx.x;          // 1024 threads == CTX_
    hist[t] = 0;
    __syncthreads();
    #pragma unroll
    for (int r = 0; r < (B_ * S_) / 1024; ++r)
        atomicAdd(&hist[ids[t + 1024 * r]], 1);
    __syncthreads();
    counts[t] = hist[t];
}

// Round-10 fused kernel with P1/P5 retiled to tokens/wave = 8:
//   P1: 8 waves = 8 col-slices of 72; pW1 loaded ONCE per block (was 2x);
//       group x16 -> 18 latency exposures (was 36).
//   P5: 8 waves = 4 col-slices x 2 k-halves (k-split merged through LDS
//       scratch overlaid on dead va); fW2 loaded once per block; 16
//       exposures per wave (was 64).
// Per-CU weight traffic 4.8 -> 2.45 MB. Everything else round-10 verbatim.
__global__ __launch_bounds__(512, 4) void token_mlp_scale_kernel(
    const int* __restrict__ ids, const int* __restrict__ counts,
    const float* __restrict__ embW,
    const float* __restrict__ lnvw, const float* __restrict__ lnvb,
    const float* __restrict__ pW1, const float* __restrict__ pb1,
    const float* __restrict__ pW2, const float* __restrict__ pb2,
    const float* __restrict__ lncw, const float* __restrict__ lncb,
    const float* __restrict__ fW1, const float* __restrict__ fb1,
    const float* __restrict__ fW2, const float* __restrict__ fb2,
    const float* __restrict__ fW3, const float* __restrict__ fb3,
    const vfloat4* __restrict__ scores, vfloat4* __restrict__ out)
{
    // activations transposed: [dim][token]; 8-token row = 32 B
    __shared__ __align__(16) float va[VD_][TPB_];      //  9.2 KB (P5 scratch after P1)
    __shared__ __align__(16) float ha[VD2_][TPB_];     // 18.4 KB
    __shared__ __align__(16) float comb17[NH1_][TPB_]; //  0.5 KB
    __shared__ __align__(16) float h2a[FFN_][TPB_];    // 16.4 KB
    __shared__ __align__(16) float h3a[FFNH_][TPB_];   //  8.2 KB
    __shared__ float wl[TPB_];
    // total 52.8 KB -> 2 blocks/CU

    const int tid  = threadIdx.x;
    const int tok0 = blockIdx.x * TPB_;
    const int wid  = tid >> 6;     // wave 0..7
    const int cthr = tid & 63;
    const int quad = wid & 1;      // token quad (P4 mapping)
    const int cq   = wid >> 1;     // column quarter (P4 mapping)
    const int tq   = quad * 4;

    // ---- phase 0: embedding gather + LayerNorm(288); one wave per token ----
    {
        const int w  = wid;          // token 0..7
        const int l  = cthr;
        const int id = ids[tok0 + w];
        float x[5];
        float s = 0.f, sq = 0.f;
        #pragma unroll
        for (int r = 0; r < 4; ++r) {
            float xv = embW[id * VD_ + l + 64 * r];
            x[r] = xv; s += xv; sq += xv * xv;
        }
        x[4] = 0.f;
        if (l < 32) {
            float xv = embW[id * VD_ + 256 + l];
            x[4] = xv; s += xv; sq += xv * xv;
        }
        #pragma unroll
        for (int m = 32; m >= 1; m >>= 1) {
            s  += __shfl_xor(s,  m, 64);
            sq += __shfl_xor(sq, m, 64);
        }
        float mu   = s * (1.f / VD_);
        float var  = sq * (1.f / VD_) - mu * mu;
        float rstd = rsqrtf(var + LN_EPS_);
        #pragma unroll
        for (int r = 0; r < 4; ++r) {
            int i = l + 64 * r;
            va[i][w] = (x[r] - mu) * rstd * lnvw[i] + lnvb[i];
        }
        if (l < 32) {
            int i = 256 + l;
            va[i][w] = (x[4] - mu) * rstd * lnvw[i] + lnvb[i];
        }
    }
    __syncthreads();

    // ---- phase 1: ha = gelu(va @ pW1 + pb1) [288 -> 576] ----
    // wave = ALL 8 tokens x 72-col slice; k grouped x16 (18 exposures);
    // pW1 element loaded once per block.
    {
        const int cb = 72 * wid;             // column slice base
        const bool extra = (cthr < 8);       // cols cb+64..cb+71
        vfloat4 a0l = 0, a0h = 0, a1l = 0, a1h = 0;
        for (int k = 0; k < VD_; k += 16) {  // 18 groups
            float w0[16], w1[16];
            #pragma unroll
            for (int u = 0; u < 16; ++u) {
                const float* wr = &pW1[(k + u) * VD2_ + cb + cthr];
                w0[u] = wr[0];
                if (extra) w1[u] = wr[64];
            }
            #pragma unroll
            for (int u = 0; u < 16; ++u) {
                vfloat4 vl = *(const vfloat4*)&va[k + u][0];
                vfloat4 vh = *(const vfloat4*)&va[k + u][4];
                a0l += w0[u] * vl; a0h += w0[u] * vh;
                if (extra) { a1l += w1[u] * vl; a1h += w1[u] * vh; }
            }
        }
        int col = cb + cthr;
        float b0 = pb1[col];
        *(vfloat4*)&ha[col][0] = gelu4(a0l + b0);
        *(vfloat4*)&ha[col][4] = gelu4(a0h + b0);
        if (extra) {
            float b1 = pb1[col + 64];
            *(vfloat4*)&ha[col + 64][0] = gelu4(a1l + b1);
            *(vfloat4*)&ha[col + 64][4] = gelu4(a1h + b1);
        }
    }
    __syncthreads();

    // ---- phase 2: valence = tanh(ha @ pW2 + pb2) [576 -> 16] + occ ----
    // waves 0..3 only; k grouped x8 (round-7 proven)
    if (wid < 4) {
        const int t0  = wid * 2;
        const int col = cthr & 15;
        const int ks  = cthr >> 4;      // 4-way K split (144 each)
        float2 acc = make_float2(0.f, 0.f);
        for (int k = ks * 144; k < ks * 144 + 144; k += 8) {
            float w[8]; float2 v[8];
            #pragma unroll
            for (int u = 0; u < 8; ++u) w[u] = pW2[(k + u) * H_ + col];
            #pragma unroll
            for (int u = 0; u < 8; ++u) v[u] = *(const float2*)&ha[k + u][t0];
            #pragma unroll
            for (int u = 0; u < 8; ++u) {
                acc.x += w[u] * v[u].x; acc.y += w[u] * v[u].y;
            }
        }
        acc.x += __shfl_xor(acc.x, 16, 64); acc.y += __shfl_xor(acc.y, 16, 64);
        acc.x += __shfl_xor(acc.x, 32, 64); acc.y += __shfl_xor(acc.y, 32, 64);
        if (cthr < 16) {
            float b = pb2[col];
            float2 o = make_float2(tanhf(acc.x + b), tanhf(acc.y + b));
            *(float2*)&comb17[1 + col][t0] = o;
        }
        if (cthr == 16) {
            #pragma unroll
            for (int j = 0; j < 2; ++j) {
                int t = t0 + j;
                int id = ids[tok0 + t];
                float c = (float)counts[id];
                if (c < 1.f) c = 1.f;
                comb17[0][t] = log1pf(c);
            }
        }
    }
    __syncthreads();

    // ---- phase 3: LayerNorm(17), one thread per token ----
    if (tid < TPB_) {
        float vals[NH1_];
        float s = 0.f;
        #pragma unroll
        for (int i = 0; i < NH1_; ++i) { vals[i] = comb17[i][tid]; s += vals[i]; }
        float mu = s / NH1_;
        float vq = 0.f;
        #pragma unroll
        for (int i = 0; i < NH1_; ++i) { float d = vals[i] - mu; vq += d * d; }
        float r = rsqrtf(vq / NH1_ + LN_EPS_);
        #pragma unroll
        for (int i = 0; i < NH1_; ++i)
            comb17[i][tid] = (vals[i] - mu) * r * lncw[i] + lncb[i];
    }
    __syncthreads();

    // ---- phase 4: h2 = gelu(comb @ fW1 + fb1) [17 -> 512] ----
    // wave = 4 tokens x 128 cols (quarter); 17 k fully unrolled, fan-2
    {
        vfloat4 a0 = 0, a1 = 0;
        const int cb = 128 * cq;
        #pragma unroll
        for (int k = 0; k < NH1_; ++k) {
            vfloat4 v = *(const vfloat4*)&comb17[k][tq];
            const float* wr = &fW1[k * FFN_ + cb + cthr];
            a0 += wr[0] * v;
            a1 += wr[64] * v;
        }
        int col = cb + cthr;
        *(vfloat4*)&h2a[col     ][tq] = gelu4(a0 + fb1[col]);
        *(vfloat4*)&h2a[col + 64][tq] = gelu4(a1 + fb1[col + 64]);
    }
    __syncthreads();

    // ---- phase 5: h3 = gelu(h2 @ fW2 + fb2) [512 -> 256] ----
    // wave = ALL 8 tokens x 64-col slice x half-k; k grouped x16
    // (16 exposures/wave); fW2 element loaded once per block.
    // k-halves merged through scratch overlaid on dead va.
    {
        float* part = (float*)va;          // 2048 floats needed, va = 2304 ✓
        const int cs = wid & 3;            // col slice 0..3
        const int kh = wid >> 2;           // k half 0/1
        const int cb = 64 * cs;
        const int k0 = kh * 256;
        vfloat4 a0l = 0, a0h = 0;
        for (int k = k0; k < k0 + 256; k += 16) {   // 16 groups
            float w0[16];
            #pragma unroll
            for (int u = 0; u < 16; ++u)
                w0[u] = fW2[(k + u) * FFNH_ + cb + cthr];
            #pragma unroll
            for (int u = 0; u < 16; ++u) {
                vfloat4 vl = *(const vfloat4*)&h2a[k + u][0];
                vfloat4 vh = *(const vfloat4*)&h2a[k + u][4];
                a0l += w0[u] * vl; a0h += w0[u] * vh;
            }
        }
        const int col = cb + cthr;
        if (kh) {
            *(vfloat4*)&part[col * 8 + 0] = a0l;
            *(vfloat4*)&part[col * 8 + 4] = a0h;
        }
        __syncthreads();
        if (!kh) {
            vfloat4 pl = *(const vfloat4*)&part[col * 8 + 0];
            vfloat4 ph = *(const vfloat4*)&part[col * 8 + 4];
            float b = fb2[col];
            *(vfloat4*)&h3a[col][0] = gelu4(a0l + pl + b);
            *(vfloat4*)&h3a[col][4] = gelu4(a0h + ph + b);
        }
    }
    __syncthreads();

    // ---- phase 6: mod = tanh(h3 . fW3 + fb3); one wave per token ----
    {
        const int tt = wid;
        const int l  = cthr;
        float acc = 0.f;
        #pragma unroll
        for (int r = 0; r < FFNH_ / 64; ++r) {
            int k = l + 64 * r;
            acc += h3a[k][tt] * fW3[k];
        }
        #pragma unroll
        for (int m = 32; m >= 1; m >>= 1) acc += __shfl_xor(acc, m, 64);
        if (l == 0)
            wl[tt] = 1.0f + EPSILON_ * tanhf(acc + fb3[0]);
    }
    __syncthreads();

    // ---- fused scale: this block's 8 tokens x 16 heads x 2048 floats ----
    {
        const int g0 = blockIdx.x * TPB_;
        #pragma unroll 4
        for (int m = tid; m < TPB_ * H_ * (S_ / 4); m += 512) {
            int rr  = m >> 9;             // local row 0..127
            int off = m & 511;
            int j   = rr & 7;             // token within block
            int h   = rr >> 3;            // head
            int g   = g0 + j;
            long row = (long)(g >> 11) * (H_ * S_) + h * S_ + (g & (S_ - 1));
            long idx = row * (S_ / 4) + off;
            vfloat4 x = __builtin_nontemporal_load(&scores[idx]);
            x *= wl[j];
            __builtin_nontemporal_store(x, &out[idx]);
        }
    }
}

extern "C" void kernel_launch(void* const* d_in, const int* in_sizes, int n_in,
                              void* d_out, int out_size, void* d_ws, size_t ws_size,
                              hipStream_t stream) {
    const float* scores = (const float*)d_in[0];
    const int*   ids    = (const int*)  d_in[1];
    const float* embW   = (const float*)d_in[2];
    const float* lnvw   = (const float*)d_in[3];
    const float* lnvb   = (const float*)d_in[4];
    const float* pW1    = (const float*)d_in[5];
    const float* pb1    = (const float*)d_in[6];
    const float* pW2    = (const float*)d_in[7];
    const float* pb2    = (const float*)d_in[8];
    const float* lncw   = (const float*)d_in[9];
    const float* lncb   = (const float*)d_in[10];
    const float* fW1    = (const float*)d_in[11];
    const float* fb1    = (const float*)d_in[12];
    const float* fW2    = (const float*)d_in[13];
    const float* fb2    = (const float*)d_in[14];
    const float* fW3    = (const float*)d_in[15];
    const float* fb3    = (const float*)d_in[16];

    int* counts = (int*)d_ws;

    count_kernel<<<1, 1024, 0, stream>>>(ids, counts);
    token_mlp_scale_kernel<<<NBLK_, 512, 0, stream>>>(
        ids, counts, embW, lnvw, lnvb, pW1, pb1, pW2, pb2,
        lncw, lncb, fW1, fb1, fW2, fb2, fW3, fb3,
        (const vfloat4*)scores, (vfloat4*)d_out);
}

// Round 12
// 254.742 us; speedup vs baseline: 1.0144x; 1.0144x over previous
//
#include <hip/hip_runtime.h>
#include <math.h>

#define B_ 2
#define H_ 16
#define S_ 2048
#define CTX_ 1024
#define VD_ 288
#define VD2_ 576
#define FFN_ 512
#define FFNH_ 256
#define NH1_ 17
#define EPSILON_ 0.066f
#define LN_EPS_ 1e-5f
#define TPB_ 8                    // tokens per block
#define NBLK_ (B_ * S_ / TPB_)    // 512 blocks -> 2 blocks/CU

typedef float vfloat4 __attribute__((ext_vector_type(4)));

__device__ __forceinline__ float gelu_exact(float x) {
    return 0.5f * x * (1.0f + erff(x * 0.70710678118654752440f));
}
__device__ __forceinline__ vfloat4 gelu4(vfloat4 v) {
    vfloat4 o;
    o.x = gelu_exact(v.x); o.y = gelu_exact(v.y);
    o.z = gelu_exact(v.z); o.w = gelu_exact(v.w);
    return o;
}

// one-block fused histogram (proven round 4)
__global__ __launch_bounds__(1024) void count_kernel(
    const int* __restrict__ ids, int* __restrict__ counts)
{
    __shared__ int hist[CTX_];
    const int t = threadIdx.x;          // 1024 threads == CTX_
    hist[t] = 0;
    __syncthreads();
    #pragma unroll
    for (int r = 0; r < (B_ * S_) / 1024; ++r)
        atomicAdd(&hist[ids[t + 1024 * r]], 1);
    __syncthreads();
    counts[t] = hist[t];
}

// Round-10 fused kernel (proven 249.2) + P5 retile ONLY (A/B to isolate
// round-11's regression): P5 = 8 waves = 4 col-slices x 2 k-halves, fW2
// loaded once per block, 16 latency exposures (was 64), k-halves merged
// through scratch overlaid on dead va. P1 kept in round-10 form (single
// LDS broadcast per k — round-11's 8-token P1 doubled LDS reads, suspect).
__global__ __launch_bounds__(512, 4) void token_mlp_scale_kernel(
    const int* __restrict__ ids, const int* __restrict__ counts,
    const float* __restrict__ embW,
    const float* __restrict__ lnvw, const float* __restrict__ lnvb,
    const float* __restrict__ pW1, const float* __restrict__ pb1,
    const float* __restrict__ pW2, const float* __restrict__ pb2,
    const float* __restrict__ lncw, const float* __restrict__ lncb,
    const float* __restrict__ fW1, const float* __restrict__ fb1,
    const float* __restrict__ fW2, const float* __restrict__ fb2,
    const float* __restrict__ fW3, const float* __restrict__ fb3,
    const vfloat4* __restrict__ scores, vfloat4* __restrict__ out)
{
    // activations transposed: [dim][token]; 8-token row = 32 B
    __shared__ __align__(16) float va[VD_][TPB_];      //  9.2 KB (P5 scratch after P1)
    __shared__ __align__(16) float ha[VD2_][TPB_];     // 18.4 KB
    __shared__ __align__(16) float comb17[NH1_][TPB_]; //  0.5 KB
    __shared__ __align__(16) float h2a[FFN_][TPB_];    // 16.4 KB
    __shared__ __align__(16) float h3a[FFNH_][TPB_];   //  8.2 KB
    __shared__ float wl[TPB_];
    // total 52.8 KB -> 2 blocks/CU

    const int tid  = threadIdx.x;
    const int tok0 = blockIdx.x * TPB_;
    const int wid  = tid >> 6;     // wave 0..7
    const int cthr = tid & 63;
    const int quad = wid & 1;      // token quad 0/1 (tokens 4q..4q+3)
    const int cq   = wid >> 1;     // column quarter 0..3
    const int tq   = quad * 4;

    // ---- phase 0: embedding gather + LayerNorm(288); one wave per token ----
    {
        const int w  = wid;          // token 0..7
        const int l  = cthr;
        const int id = ids[tok0 + w];
        float x[5];
        float s = 0.f, sq = 0.f;
        #pragma unroll
        for (int r = 0; r < 4; ++r) {
            float xv = embW[id * VD_ + l + 64 * r];
            x[r] = xv; s += xv; sq += xv * xv;
        }
        x[4] = 0.f;
        if (l < 32) {
            float xv = embW[id * VD_ + 256 + l];
            x[4] = xv; s += xv; sq += xv * xv;
        }
        #pragma unroll
        for (int m = 32; m >= 1; m >>= 1) {
            s  += __shfl_xor(s,  m, 64);
            sq += __shfl_xor(sq, m, 64);
        }
        float mu   = s * (1.f / VD_);
        float var  = sq * (1.f / VD_) - mu * mu;
        float rstd = rsqrtf(var + LN_EPS_);
        #pragma unroll
        for (int r = 0; r < 4; ++r) {
            int i = l + 64 * r;
            va[i][w] = (x[r] - mu) * rstd * lnvw[i] + lnvb[i];
        }
        if (l < 32) {
            int i = 256 + l;
            va[i][w] = (x[4] - mu) * rstd * lnvw[i] + lnvb[i];
        }
    }
    __syncthreads();

    // ---- phase 1: ha = gelu(va @ pW1 + pb1) [288 -> 576] ----
    // wave = 4 tokens x 144 cols (quarter); k grouped x8, fan 2.25
    // (round-10 form: ONE vfloat4 broadcast per k)
    {
        vfloat4 a0 = 0, a1 = 0, a2 = 0;
        const int cb = 144 * cq;
        const bool extra = (cthr < 16);        // cols cb+128..cb+143
        for (int k = 0; k < VD_; k += 8) {     // 36 groups
            float w0[8], w1[8], w2[8];
            #pragma unroll
            for (int u = 0; u < 8; ++u) {
                const float* wr = &pW1[(k + u) * VD2_ + cb + cthr];
                w0[u] = wr[0]; w1[u] = wr[64];
                if (extra) w2[u] = wr[128];
            }
            vfloat4 v[8];
            #pragma unroll
            for (int u = 0; u < 8; ++u) v[u] = *(const vfloat4*)&va[k + u][tq];
            #pragma unroll
            for (int u = 0; u < 8; ++u) {
                a0 += w0[u] * v[u];
                a1 += w1[u] * v[u];
                if (extra) a2 += w2[u] * v[u];
            }
        }
        int col = cb + cthr;
        *(vfloat4*)&ha[col     ][tq] = gelu4(a0 + pb1[col]);
        *(vfloat4*)&ha[col + 64][tq] = gelu4(a1 + pb1[col + 64]);
        if (extra)
            *(vfloat4*)&ha[col + 128][tq] = gelu4(a2 + pb1[col + 128]);
    }
    __syncthreads();

    // ---- phase 2: valence = tanh(ha @ pW2 + pb2) [576 -> 16] + occ ----
    // waves 0..3 only; k grouped x8 (round-7 proven)
    if (wid < 4) {
        const int t0  = wid * 2;
        const int col = cthr & 15;
        const int ks  = cthr >> 4;      // 4-way K split (144 each)
        float2 acc = make_float2(0.f, 0.f);
        for (int k = ks * 144; k < ks * 144 + 144; k += 8) {
            float w[8]; float2 v[8];
            #pragma unroll
            for (int u = 0; u < 8; ++u) w[u] = pW2[(k + u) * H_ + col];
            #pragma unroll
            for (int u = 0; u < 8; ++u) v[u] = *(const float2*)&ha[k + u][t0];
            #pragma unroll
            for (int u = 0; u < 8; ++u) {
                acc.x += w[u] * v[u].x; acc.y += w[u] * v[u].y;
            }
        }
        acc.x += __shfl_xor(acc.x, 16, 64); acc.y += __shfl_xor(acc.y, 16, 64);
        acc.x += __shfl_xor(acc.x, 32, 64); acc.y += __shfl_xor(acc.y, 32, 64);
        if (cthr < 16) {
            float b = pb2[col];
            float2 o = make_float2(tanhf(acc.x + b), tanhf(acc.y + b));
            *(float2*)&comb17[1 + col][t0] = o;
        }
        if (cthr == 16) {
            #pragma unroll
            for (int j = 0; j < 2; ++j) {
                int t = t0 + j;
                int id = ids[tok0 + t];
                float c = (float)counts[id];
                if (c < 1.f) c = 1.f;
                comb17[0][t] = log1pf(c);
            }
        }
    }
    __syncthreads();

    // ---- phase 3: LayerNorm(17), one thread per token ----
    if (tid < TPB_) {
        float vals[NH1_];
        float s = 0.f;
        #pragma unroll
        for (int i = 0; i < NH1_; ++i) { vals[i] = comb17[i][tid]; s += vals[i]; }
        float mu = s / NH1_;
        float vq = 0.f;
        #pragma unroll
        for (int i = 0; i < NH1_; ++i) { float d = vals[i] - mu; vq += d * d; }
        float r = rsqrtf(vq / NH1_ + LN_EPS_);
        #pragma unroll
        for (int i = 0; i < NH1_; ++i)
            comb17[i][tid] = (vals[i] - mu) * r * lncw[i] + lncb[i];
    }
    __syncthreads();

    // ---- phase 4: h2 = gelu(comb @ fW1 + fb1) [17 -> 512] ----
    // wave = 4 tokens x 128 cols (quarter); 17 k fully unrolled, fan-2
    {
        vfloat4 a0 = 0, a1 = 0;
        const int cb = 128 * cq;
        #pragma unroll
        for (int k = 0; k < NH1_; ++k) {
            vfloat4 v = *(const vfloat4*)&comb17[k][tq];
            const float* wr = &fW1[k * FFN_ + cb + cthr];
            a0 += wr[0] * v;
            a1 += wr[64] * v;
        }
        int col = cb + cthr;
        *(vfloat4*)&h2a[col     ][tq] = gelu4(a0 + fb1[col]);
        *(vfloat4*)&h2a[col + 64][tq] = gelu4(a1 + fb1[col + 64]);
    }
    __syncthreads();

    // ---- phase 5: h3 = gelu(h2 @ fW2 + fb2) [512 -> 256] ----
    // RETILED (round-11 form): wave = ALL 8 tokens x 64-col slice x half-k;
    // k grouped x16 (16 exposures/wave); fW2 loaded once per block.
    // k-halves merged through scratch overlaid on dead va.
    {
        float* part = (float*)va;          // 2048 floats needed, va = 2304 ✓
        const int cs = wid & 3;            // col slice 0..3
        const int kh = wid >> 2;           // k half 0/1
        const int cb = 64 * cs;
        const int k0 = kh * 256;
        vfloat4 a0l = 0, a0h = 0;
        for (int k = k0; k < k0 + 256; k += 16) {   // 16 groups
            float w0[16];
            #pragma unroll
            for (int u = 0; u < 16; ++u)
                w0[u] = fW2[(k + u) * FFNH_ + cb + cthr];
            #pragma unroll
            for (int u = 0; u < 16; ++u) {
                vfloat4 vl = *(const vfloat4*)&h2a[k + u][0];
                vfloat4 vh = *(const vfloat4*)&h2a[k + u][4];
                a0l += w0[u] * vl; a0h += w0[u] * vh;
            }
        }
        const int col = cb + cthr;
        if (kh) {
            *(vfloat4*)&part[col * 8 + 0] = a0l;
            *(vfloat4*)&part[col * 8 + 4] = a0h;
        }
        __syncthreads();
        if (!kh) {
            vfloat4 pl = *(const vfloat4*)&part[col * 8 + 0];
            vfloat4 ph = *(const vfloat4*)&part[col * 8 + 4];
            float b = fb2[col];
            *(vfloat4*)&h3a[col][0] = gelu4(a0l + pl + b);
            *(vfloat4*)&h3a[col][4] = gelu4(a0h + ph + b);
        }
    }
    __syncthreads();

    // ---- phase 6: mod = tanh(h3 . fW3 + fb3); one wave per token ----
    {
        const int tt = wid;
        const int l  = cthr;
        float acc = 0.f;
        #pragma unroll
        for (int r = 0; r < FFNH_ / 64; ++r) {
            int k = l + 64 * r;
            acc += h3a[k][tt] * fW3[k];
        }
        #pragma unroll
        for (int m = 32; m >= 1; m >>= 1) acc += __shfl_xor(acc, m, 64);
        if (l == 0)
            wl[tt] = 1.0f + EPSILON_ * tanhf(acc + fb3[0]);
    }
    __syncthreads();

    // ---- fused scale: this block's 8 tokens x 16 heads x 2048 floats ----
    {
        const int g0 = blockIdx.x * TPB_;
        #pragma unroll 4
        for (int m = tid; m < TPB_ * H_ * (S_ / 4); m += 512) {
            int rr  = m >> 9;             // local row 0..127
            int off = m & 511;
            int j   = rr & 7;             // token within block
            int h   = rr >> 3;            // head
            int g   = g0 + j;
            long row = (long)(g >> 11) * (H_ * S_) + h * S_ + (g & (S_ - 1));
            long idx = row * (S_ / 4) + off;
            vfloat4 x = __builtin_nontemporal_load(&scores[idx]);
            x *= wl[j];
            __builtin_nontemporal_store(x, &out[idx]);
        }
    }
}

extern "C" void kernel_launch(void* const* d_in, const int* in_sizes, int n_in,
                              void* d_out, int out_size, void* d_ws, size_t ws_size,
                              hipStream_t stream) {
    const float* scores = (const float*)d_in[0];
    const int*   ids    = (const int*)  d_in[1];
    const float* embW   = (const float*)d_in[2];
    const float* lnvw   = (const float*)d_in[3];
    const float* lnvb   = (const float*)d_in[4];
    const float* pW1    = (const float*)d_in[5];
    const float* pb1    = (const float*)d_in[6];
    const float* pW2    = (const float*)d_in[7];
    const float* pb2    = (const float*)d_in[8];
    const float* lncw   = (const float*)d_in[9];
    const float* lncb   = (const float*)d_in[10];
    const float* fW1    = (const float*)d_in[11];
    const float* fb1    = (const float*)d_in[12];
    const float* fW2    = (const float*)d_in[13];
    const float* fb2    = (const float*)d_in[14];
    const float* fW3    = (const float*)d_in[15];
    const float* fb3    = (const float*)d_in[16];

    int* counts = (int*)d_ws;

    count_kernel<<<1, 1024, 0, stream>>>(ids, counts);
    token_mlp_scale_kernel<<<NBLK_, 512, 0, stream>>>(
        ids, counts, embW, lnvw, lnvb, pW1, pb1, pW2, pb2,
        lncw, lncb, fW1, fb1, fW2, fb2, fW3, fb3,
        (const vfloat4*)scores, (vfloat4*)d_out);
}

// Round 13
// 252.471 us; speedup vs baseline: 1.0235x; 1.0090x over previous
//
#include <hip/hip_runtime.h>
#include <math.h>

#define B_ 2
#define H_ 16
#define S_ 2048
#define CTX_ 1024
#define VD_ 288
#define VD2_ 576
#define FFN_ 512
#define FFNH_ 256
#define NH1_ 17
#define EPSILON_ 0.066f
#define LN_EPS_ 1e-5f
#define TPB_ 8                    // tokens per block
#define NBLK_ (B_ * S_ / TPB_)    // 512 blocks -> 2 blocks/CU

typedef float vfloat4 __attribute__((ext_vector_type(4)));

__device__ __forceinline__ float gelu_exact(float x) {
    return 0.5f * x * (1.0f + erff(x * 0.70710678118654752440f));
}
__device__ __forceinline__ vfloat4 gelu4(vfloat4 v) {
    vfloat4 o;
    o.x = gelu_exact(v.x); o.y = gelu_exact(v.y);
    o.z = gelu_exact(v.z); o.w = gelu_exact(v.w);
    return o;
}

// Round-10 fused kernel (proven 249.2) + two conservative changes:
//  (a) token histogram folded in: each block redundantly counts all 4096
//      ids in LDS (identical semantics; kills the serial count kernel).
//  (b) P5 prefetch group x8 -> x16, SAME tiling (exposures 64 -> 32;
//      the knob proven in r6->r7 and r9->r10).
__global__ __launch_bounds__(512, 4) void token_mlp_scale_kernel(
    const int* __restrict__ ids,
    const float* __restrict__ embW,
    const float* __restrict__ lnvw, const float* __restrict__ lnvb,
    const float* __restrict__ pW1, const float* __restrict__ pb1,
    const float* __restrict__ pW2, const float* __restrict__ pb2,
    const float* __restrict__ lncw, const float* __restrict__ lncb,
    const float* __restrict__ fW1, const float* __restrict__ fb1,
    const float* __restrict__ fW2, const float* __restrict__ fb2,
    const float* __restrict__ fW3, const float* __restrict__ fb3,
    const vfloat4* __restrict__ scores, vfloat4* __restrict__ out)
{
    // activations transposed: [dim][token]; 8-token row = 32 B
    __shared__ __align__(16) float va[VD_][TPB_];      //  9.2 KB
    __shared__ __align__(16) float ha[VD2_][TPB_];     // 18.4 KB
    __shared__ __align__(16) float comb17[NH1_][TPB_]; //  0.5 KB
    __shared__ __align__(16) float h2a[FFN_][TPB_];    // 16.4 KB
    __shared__ __align__(16) float h3a[FFNH_][TPB_];   //  8.2 KB
    __shared__ int hist[CTX_];                         //  4.0 KB
    __shared__ float wl[TPB_];
    // total 56.8 KB -> 2 blocks/CU

    const int tid  = threadIdx.x;
    const int tok0 = blockIdx.x * TPB_;
    const int wid  = tid >> 6;     // wave 0..7
    const int cthr = tid & 63;
    const int quad = wid & 1;      // token quad 0/1 (tokens 4q..4q+3)
    const int cq   = wid >> 1;     // column quarter 0..3
    const int tq   = quad * 4;

    // ---- histogram init (folded count kernel) ----
    hist[tid] = 0;
    hist[tid + 512] = 0;
    __syncthreads();
    #pragma unroll
    for (int r = 0; r < (B_ * S_) / 512; ++r)      // 8 coalesced reads
        atomicAdd(&hist[ids[tid + 512 * r]], 1);
    // completion covered by the phase-0 barrier below

    // ---- phase 0: embedding gather + LayerNorm(288); one wave per token ----
    {
        const int w  = wid;          // token 0..7
        const int l  = cthr;
        const int id = ids[tok0 + w];
        float x[5];
        float s = 0.f, sq = 0.f;
        #pragma unroll
        for (int r = 0; r < 4; ++r) {
            float xv = embW[id * VD_ + l + 64 * r];
            x[r] = xv; s += xv; sq += xv * xv;
        }
        x[4] = 0.f;
        if (l < 32) {
            float xv = embW[id * VD_ + 256 + l];
            x[4] = xv; s += xv; sq += xv * xv;
        }
        #pragma unroll
        for (int m = 32; m >= 1; m >>= 1) {
            s  += __shfl_xor(s,  m, 64);
            sq += __shfl_xor(sq, m, 64);
        }
        float mu   = s * (1.f / VD_);
        float var  = sq * (1.f / VD_) - mu * mu;
        float rstd = rsqrtf(var + LN_EPS_);
        #pragma unroll
        for (int r = 0; r < 4; ++r) {
            int i = l + 64 * r;
            va[i][w] = (x[r] - mu) * rstd * lnvw[i] + lnvb[i];
        }
        if (l < 32) {
            int i = 256 + l;
            va[i][w] = (x[4] - mu) * rstd * lnvw[i] + lnvb[i];
        }
    }
    __syncthreads();

    // ---- phase 1: ha = gelu(va @ pW1 + pb1) [288 -> 576] ----
    // wave = 4 tokens x 144 cols (quarter); k grouped x8, fan 2.25
    {
        vfloat4 a0 = 0, a1 = 0, a2 = 0;
        const int cb = 144 * cq;
        const bool extra = (cthr < 16);        // cols cb+128..cb+143
        for (int k = 0; k < VD_; k += 8) {     // 36 groups
            float w0[8], w1[8], w2[8];
            #pragma unroll
            for (int u = 0; u < 8; ++u) {
                const float* wr = &pW1[(k + u) * VD2_ + cb + cthr];
                w0[u] = wr[0]; w1[u] = wr[64];
                if (extra) w2[u] = wr[128];
            }
            vfloat4 v[8];
            #pragma unroll
            for (int u = 0; u < 8; ++u) v[u] = *(const vfloat4*)&va[k + u][tq];
            #pragma unroll
            for (int u = 0; u < 8; ++u) {
                a0 += w0[u] * v[u];
                a1 += w1[u] * v[u];
                if (extra) a2 += w2[u] * v[u];
            }
        }
        int col = cb + cthr;
        *(vfloat4*)&ha[col     ][tq] = gelu4(a0 + pb1[col]);
        *(vfloat4*)&ha[col + 64][tq] = gelu4(a1 + pb1[col + 64]);
        if (extra)
            *(vfloat4*)&ha[col + 128][tq] = gelu4(a2 + pb1[col + 128]);
    }
    __syncthreads();

    // ---- phase 2: valence = tanh(ha @ pW2 + pb2) [576 -> 16] + occ ----
    // waves 0..3 only; k grouped x8 (round-7 proven)
    if (wid < 4) {
        const int t0  = wid * 2;
        const int col = cthr & 15;
        const int ks  = cthr >> 4;      // 4-way K split (144 each)
        float2 acc = make_float2(0.f, 0.f);
        for (int k = ks * 144; k < ks * 144 + 144; k += 8) {
            float w[8]; float2 v[8];
            #pragma unroll
            for (int u = 0; u < 8; ++u) w[u] = pW2[(k + u) * H_ + col];
            #pragma unroll
            for (int u = 0; u < 8; ++u) v[u] = *(const float2*)&ha[k + u][t0];
            #pragma unroll
            for (int u = 0; u < 8; ++u) {
                acc.x += w[u] * v[u].x; acc.y += w[u] * v[u].y;
            }
        }
        acc.x += __shfl_xor(acc.x, 16, 64); acc.y += __shfl_xor(acc.y, 16, 64);
        acc.x += __shfl_xor(acc.x, 32, 64); acc.y += __shfl_xor(acc.y, 32, 64);
        if (cthr < 16) {
            float b = pb2[col];
            float2 o = make_float2(tanhf(acc.x + b), tanhf(acc.y + b));
            *(float2*)&comb17[1 + col][t0] = o;
        }
        if (cthr == 16) {
            #pragma unroll
            for (int j = 0; j < 2; ++j) {
                int t = t0 + j;
                int id = ids[tok0 + t];
                float c = (float)hist[id];
                if (c < 1.f) c = 1.f;
                comb17[0][t] = log1pf(c);
            }
        }
    }
    __syncthreads();

    // ---- phase 3: LayerNorm(17), one thread per token ----
    if (tid < TPB_) {
        float vals[NH1_];
        float s = 0.f;
        #pragma unroll
        for (int i = 0; i < NH1_; ++i) { vals[i] = comb17[i][tid]; s += vals[i]; }
        float mu = s / NH1_;
        float vq = 0.f;
        #pragma unroll
        for (int i = 0; i < NH1_; ++i) { float d = vals[i] - mu; vq += d * d; }
        float r = rsqrtf(vq / NH1_ + LN_EPS_);
        #pragma unroll
        for (int i = 0; i < NH1_; ++i)
            comb17[i][tid] = (vals[i] - mu) * r * lncw[i] + lncb[i];
    }
    __syncthreads();

    // ---- phase 4: h2 = gelu(comb @ fW1 + fb1) [17 -> 512] ----
    // wave = 4 tokens x 128 cols (quarter); 17 k fully unrolled, fan-2
    {
        vfloat4 a0 = 0, a1 = 0;
        const int cb = 128 * cq;
        #pragma unroll
        for (int k = 0; k < NH1_; ++k) {
            vfloat4 v = *(const vfloat4*)&comb17[k][tq];
            const float* wr = &fW1[k * FFN_ + cb + cthr];
            a0 += wr[0] * v;
            a1 += wr[64] * v;
        }
        int col = cb + cthr;
        *(vfloat4*)&h2a[col     ][tq] = gelu4(a0 + fb1[col]);
        *(vfloat4*)&h2a[col + 64][tq] = gelu4(a1 + fb1[col + 64]);
    }
    __syncthreads();

    // ---- phase 5: h3 = gelu(h2 @ fW2 + fb2) [512 -> 256] ----
    // wave = 4 tokens x 64 cols (quarter); fan-1, k grouped x16
    // (same tiling as round 10, exposures 64 -> 32)
    {
        vfloat4 a0 = 0;
        const int cb = 64 * cq;
        for (int k = 0; k < FFN_; k += 16) {   // 32 groups
            float w0[16]; vfloat4 v[16];
            #pragma unroll
            for (int u = 0; u < 16; ++u)
                w0[u] = fW2[(k + u) * FFNH_ + cb + cthr];
            #pragma unroll
            for (int u = 0; u < 16; ++u) v[u] = *(const vfloat4*)&h2a[k + u][tq];
            #pragma unroll
            for (int u = 0; u < 16; ++u) a0 += w0[u] * v[u];
        }
        int col = cb + cthr;
        *(vfloat4*)&h3a[col][tq] = gelu4(a0 + fb2[col]);
    }
    __syncthreads();

    // ---- phase 6: mod = tanh(h3 . fW3 + fb3); one wave per token ----
    {
        const int tt = wid;
        const int l  = cthr;
        float acc = 0.f;
        #pragma unroll
        for (int r = 0; r < FFNH_ / 64; ++r) {
            int k = l + 64 * r;
            acc += h3a[k][tt] * fW3[k];
        }
        #pragma unroll
        for (int m = 32; m >= 1; m >>= 1) acc += __shfl_xor(acc, m, 64);
        if (l == 0)
            wl[tt] = 1.0f + EPSILON_ * tanhf(acc + fb3[0]);
    }
    __syncthreads();

    // ---- fused scale: this block's 8 tokens x 16 heads x 2048 floats ----
    {
        const int g0 = blockIdx.x * TPB_;
        #pragma unroll 4
        for (int m = tid; m < TPB_ * H_ * (S_ / 4); m += 512) {
            int rr  = m >> 9;             // local row 0..127
            int off = m & 511;
            int j   = rr & 7;             // token within block
            int h   = rr >> 3;            // head
            int g   = g0 + j;
            long row = (long)(g >> 11) * (H_ * S_) + h * S_ + (g & (S_ - 1));
            long idx = row * (S_ / 4) + off;
            vfloat4 x = __builtin_nontemporal_load(&scores[idx]);
            x *= wl[j];
            __builtin_nontemporal_store(x, &out[idx]);
        }
    }
}

extern "C" void kernel_launch(void* const* d_in, const int* in_sizes, int n_in,
                              void* d_out, int out_size, void* d_ws, size_t ws_size,
                              hipStream_t stream) {
    const float* scores = (const float*)d_in[0];
    const int*   ids    = (const int*)  d_in[1];
    const float* embW   = (const float*)d_in[2];
    const float* lnvw   = (const float*)d_in[3];
    const float* lnvb   = (const float*)d_in[4];
    const float* pW1    = (const float*)d_in[5];
    const float* pb1    = (const float*)d_in[6];
    const float* pW2    = (const float*)d_in[7];
    const float* pb2    = (const float*)d_in[8];
    const float* lncw   = (const float*)d_in[9];
    const float* lncb   = (const float*)d_in[10];
    const float* fW1    = (const float*)d_in[11];
    const float* fb1    = (const float*)d_in[12];
    const float* fW2    = (const float*)d_in[13];
    const float* fb2    = (const float*)d_in[14];
    const float* fW3    = (const float*)d_in[15];
    const float* fb3    = (const float*)d_in[16];

    token_mlp_scale_kernel<<<NBLK_, 512, 0, stream>>>(
        ids, embW, lnvw, lnvb, pW1, pb1, pW2, pb2,
        lncw, lncb, fW1, fb1, fW2, fb2, fW3, fb3,
        (const vfloat4*)scores, (vfloat4*)d_out);
}

// Round 14
// 251.415 us; speedup vs baseline: 1.0278x; 1.0042x over previous
//
#include <hip/hip_runtime.h>
#include <math.h>

#define B_ 2
#define H_ 16
#define S_ 2048
#define CTX_ 1024
#define VD_ 288
#define VD2_ 576
#define FFN_ 512
#define FFNH_ 256
#define NH1_ 17
#define EPSILON_ 0.066f
#define LN_EPS_ 1e-5f
#define TPB_ 8                    // tokens per block
#define NBLK_ (B_ * S_ / TPB_)    // 512 blocks -> 2 blocks/CU

typedef float vfloat4 __attribute__((ext_vector_type(4)));

__device__ __forceinline__ float gelu_exact(float x) {
    return 0.5f * x * (1.0f + erff(x * 0.70710678118654752440f));
}
__device__ __forceinline__ vfloat4 gelu4(vfloat4 v) {
    vfloat4 o;
    o.x = gelu_exact(v.x); o.y = gelu_exact(v.y);
    o.z = gelu_exact(v.z); o.w = gelu_exact(v.w);
    return o;
}

// one-block fused histogram (proven round 4)
__global__ __launch_bounds__(1024) void count_kernel(
    const int* __restrict__ ids, int* __restrict__ counts)
{
    __shared__ int hist[CTX_];
    const int t = threadIdx.x;          // 1024 threads == CTX_
    hist[t] = 0;
    __syncthreads();
    #pragma unroll
    for (int r = 0; r < (B_ * S_) / 1024; ++r)
        atomicAdd(&hist[ids[t + 1024 * r]], 1);
    __syncthreads();
    counts[t] = hist[t];
}

// EXACT round-10 kernel (proven 249.2 us — session optimum).
// TPB=8, 512 thr = 8 waves = 2 token-quads x 4 column-quarters, grouped
// register prefetch in P1/P2/P5, 52.8 KB LDS -> 2 blocks/CU = 4 waves/SIMD,
// scale stream fused at the tail with wl in LDS.
__global__ __launch_bounds__(512, 4) void token_mlp_scale_kernel(
    const int* __restrict__ ids, const int* __restrict__ counts,
    const float* __restrict__ embW,
    const float* __restrict__ lnvw, const float* __restrict__ lnvb,
    const float* __restrict__ pW1, const float* __restrict__ pb1,
    const float* __restrict__ pW2, const float* __restrict__ pb2,
    const float* __restrict__ lncw, const float* __restrict__ lncb,
    const float* __restrict__ fW1, const float* __restrict__ fb1,
    const float* __restrict__ fW2, const float* __restrict__ fb2,
    const float* __restrict__ fW3, const float* __restrict__ fb3,
    const vfloat4* __restrict__ scores, vfloat4* __restrict__ out)
{
    // activations transposed: [dim][token]; 8-token row = 32 B
    __shared__ __align__(16) float va[VD_][TPB_];      //  9.2 KB
    __shared__ __align__(16) float ha[VD2_][TPB_];     // 18.4 KB
    __shared__ __align__(16) float comb17[NH1_][TPB_]; //  0.5 KB
    __shared__ __align__(16) float h2a[FFN_][TPB_];    // 16.4 KB
    __shared__ __align__(16) float h3a[FFNH_][TPB_];   //  8.2 KB
    __shared__ float wl[TPB_];
    // total 52.8 KB -> 2 blocks/CU

    const int tid  = threadIdx.x;
    const int tok0 = blockIdx.x * TPB_;
    const int wid  = tid >> 6;     // wave 0..7
    const int cthr = tid & 63;
    const int quad = wid & 1;      // token quad 0/1 (tokens 4q..4q+3)
    const int cq   = wid >> 1;     // column quarter 0..3
    const int tq   = quad * 4;

    // ---- phase 0: embedding gather + LayerNorm(288); one wave per token ----
    {
        const int w  = wid;          // token 0..7
        const int l  = cthr;
        const int id = ids[tok0 + w];
        float x[5];
        float s = 0.f, sq = 0.f;
        #pragma unroll
        for (int r = 0; r < 4; ++r) {
            float xv = embW[id * VD_ + l + 64 * r];
            x[r] = xv; s += xv; sq += xv * xv;
        }
        x[4] = 0.f;
        if (l < 32) {
            float xv = embW[id * VD_ + 256 + l];
            x[4] = xv; s += xv; sq += xv * xv;
        }
        #pragma unroll
        for (int m = 32; m >= 1; m >>= 1) {
            s  += __shfl_xor(s,  m, 64);
            sq += __shfl_xor(sq, m, 64);
        }
        float mu   = s * (1.f / VD_);
        float var  = sq * (1.f / VD_) - mu * mu;
        float rstd = rsqrtf(var + LN_EPS_);
        #pragma unroll
        for (int r = 0; r < 4; ++r) {
            int i = l + 64 * r;
            va[i][w] = (x[r] - mu) * rstd * lnvw[i] + lnvb[i];
        }
        if (l < 32) {
            int i = 256 + l;
            va[i][w] = (x[4] - mu) * rstd * lnvw[i] + lnvb[i];
        }
    }
    __syncthreads();

    // ---- phase 1: ha = gelu(va @ pW1 + pb1) [288 -> 576] ----
    // wave = 4 tokens x 144 cols (quarter); k grouped x8, fan 2.25
    {
        vfloat4 a0 = 0, a1 = 0, a2 = 0;
        const int cb = 144 * cq;
        const bool extra = (cthr < 16);        // cols cb+128..cb+143
        for (int k = 0; k < VD_; k += 8) {     // 36 groups
            float w0[8], w1[8], w2[8];
            #pragma unroll
            for (int u = 0; u < 8; ++u) {
                const float* wr = &pW1[(k + u) * VD2_ + cb + cthr];
                w0[u] = wr[0]; w1[u] = wr[64];
                if (extra) w2[u] = wr[128];
            }
            vfloat4 v[8];
            #pragma unroll
            for (int u = 0; u < 8; ++u) v[u] = *(const vfloat4*)&va[k + u][tq];
            #pragma unroll
            for (int u = 0; u < 8; ++u) {
                a0 += w0[u] * v[u];
                a1 += w1[u] * v[u];
                if (extra) a2 += w2[u] * v[u];
            }
        }
        int col = cb + cthr;
        *(vfloat4*)&ha[col     ][tq] = gelu4(a0 + pb1[col]);
        *(vfloat4*)&ha[col + 64][tq] = gelu4(a1 + pb1[col + 64]);
        if (extra)
            *(vfloat4*)&ha[col + 128][tq] = gelu4(a2 + pb1[col + 128]);
    }
    __syncthreads();

    // ---- phase 2: valence = tanh(ha @ pW2 + pb2) [576 -> 16] + occ ----
    // waves 0..3 only; k grouped x8
    if (wid < 4) {
        const int t0  = wid * 2;
        const int col = cthr & 15;
        const int ks  = cthr >> 4;      // 4-way K split (144 each)
        float2 acc = make_float2(0.f, 0.f);
        for (int k = ks * 144; k < ks * 144 + 144; k += 8) {
            float w[8]; float2 v[8];
            #pragma unroll
            for (int u = 0; u < 8; ++u) w[u] = pW2[(k + u) * H_ + col];
            #pragma unroll
            for (int u = 0; u < 8; ++u) v[u] = *(const float2*)&ha[k + u][t0];
            #pragma unroll
            for (int u = 0; u < 8; ++u) {
                acc.x += w[u] * v[u].x; acc.y += w[u] * v[u].y;
            }
        }
        acc.x += __shfl_xor(acc.x, 16, 64); acc.y += __shfl_xor(acc.y, 16, 64);
        acc.x += __shfl_xor(acc.x, 32, 64); acc.y += __shfl_xor(acc.y, 32, 64);
        if (cthr < 16) {
            float b = pb2[col];
            float2 o = make_float2(tanhf(acc.x + b), tanhf(acc.y + b));
            *(float2*)&comb17[1 + col][t0] = o;
        }
        if (cthr == 16) {
            #pragma unroll
            for (int j = 0; j < 2; ++j) {
                int t = t0 + j;
                int id = ids[tok0 + t];
                float c = (float)counts[id];
                if (c < 1.f) c = 1.f;
                comb17[0][t] = log1pf(c);
            }
        }
    }
    __syncthreads();

    // ---- phase 3: LayerNorm(17), one thread per token ----
    if (tid < TPB_) {
        float vals[NH1_];
        float s = 0.f;
        #pragma unroll
        for (int i = 0; i < NH1_; ++i) { vals[i] = comb17[i][tid]; s += vals[i]; }
        float mu = s / NH1_;
        float vq = 0.f;
        #pragma unroll
        for (int i = 0; i < NH1_; ++i) { float d = vals[i] - mu; vq += d * d; }
        float r = rsqrtf(vq / NH1_ + LN_EPS_);
        #pragma unroll
        for (int i = 0; i < NH1_; ++i)
            comb17[i][tid] = (vals[i] - mu) * r * lncw[i] + lncb[i];
    }
    __syncthreads();

    // ---- phase 4: h2 = gelu(comb @ fW1 + fb1) [17 -> 512] ----
    // wave = 4 tokens x 128 cols (quarter); 17 k fully unrolled, fan-2
    {
        vfloat4 a0 = 0, a1 = 0;
        const int cb = 128 * cq;
        #pragma unroll
        for (int k = 0; k < NH1_; ++k) {
            vfloat4 v = *(const vfloat4*)&comb17[k][tq];
            const float* wr = &fW1[k * FFN_ + cb + cthr];
            a0 += wr[0] * v;
            a1 += wr[64] * v;
        }
        int col = cb + cthr;
        *(vfloat4*)&h2a[col     ][tq] = gelu4(a0 + fb1[col]);
        *(vfloat4*)&h2a[col + 64][tq] = gelu4(a1 + fb1[col + 64]);
    }
    __syncthreads();

    // ---- phase 5: h3 = gelu(h2 @ fW2 + fb2) [512 -> 256] ----
    // wave = 4 tokens x 64 cols (quarter); fan-1, k grouped x8
    {
        vfloat4 a0 = 0;
        const int cb = 64 * cq;
        for (int k = 0; k < FFN_; k += 8) {    // 64 groups
            float w0[8]; vfloat4 v[8];
            #pragma unroll
            for (int u = 0; u < 8; ++u)
                w0[u] = fW2[(k + u) * FFNH_ + cb + cthr];
            #pragma unroll
            for (int u = 0; u < 8; ++u) v[u] = *(const vfloat4*)&h2a[k + u][tq];
            #pragma unroll
            for (int u = 0; u < 8; ++u) a0 += w0[u] * v[u];
        }
        int col = cb + cthr;
        *(vfloat4*)&h3a[col][tq] = gelu4(a0 + fb2[col]);
    }
    __syncthreads();

    // ---- phase 6: mod = tanh(h3 . fW3 + fb3); one wave per token ----
    {
        const int tt = wid;
        const int l  = cthr;
        float acc = 0.f;
        #pragma unroll
        for (int r = 0; r < FFNH_ / 64; ++r) {
            int k = l + 64 * r;
            acc += h3a[k][tt] * fW3[k];
        }
        #pragma unroll
        for (int m = 32; m >= 1; m >>= 1) acc += __shfl_xor(acc, m, 64);
        if (l == 0)
            wl[tt] = 1.0f + EPSILON_ * tanhf(acc + fb3[0]);
    }
    __syncthreads();

    // ---- fused scale: this block's 8 tokens x 16 heads x 2048 floats ----
    {
        const int g0 = blockIdx.x * TPB_;
        #pragma unroll 4
        for (int m = tid; m < TPB_ * H_ * (S_ / 4); m += 512) {
            int rr  = m >> 9;             // local row 0..127
            int off = m & 511;
            int j   = rr & 7;             // token within block
            int h   = rr >> 3;            // head
            int g   = g0 + j;
            long row = (long)(g >> 11) * (H_ * S_) + h * S_ + (g & (S_ - 1));
            long idx = row * (S_ / 4) + off;
            vfloat4 x = __builtin_nontemporal_load(&scores[idx]);
            x *= wl[j];
            __builtin_nontemporal_store(x, &out[idx]);
        }
    }
}

extern "C" void kernel_launch(void* const* d_in, const int* in_sizes, int n_in,
                              void* d_out, int out_size, void* d_ws, size_t ws_size,
                              hipStream_t stream) {
    const float* scores = (const float*)d_in[0];
    const int*   ids    = (const int*)  d_in[1];
    const float* embW   = (const float*)d_in[2];
    const float* lnvw   = (const float*)d_in[3];
    const float* lnvb   = (const float*)d_in[4];
    const float* pW1    = (const float*)d_in[5];
    const float* pb1    = (const float*)d_in[6];
    const float* pW2    = (const float*)d_in[7];
    const float* pb2    = (const float*)d_in[8];
    const float* lncw   = (const float*)d_in[9];
    const float* lncb   = (const float*)d_in[10];
    const float* fW1    = (const float*)d_in[11];
    const float* fb1    = (const float*)d_in[12];
    const float* fW2    = (const float*)d_in[13];
    const float* fb2    = (const float*)d_in[14];
    const float* fW3    = (const float*)d_in[15];
    const float* fb3    = (const float*)d_in[16];

    int* counts = (int*)d_ws;

    count_kernel<<<1, 1024, 0, stream>>>(ids, counts);
    token_mlp_scale_kernel<<<NBLK_, 512, 0, stream>>>(
        ids, counts, embW, lnvw, lnvb, pW1, pb1, pW2, pb2,
        lncw, lncb, fW1, fb1, fW2, fb2, fW3, fb3,
        (const vfloat4*)scores, (vfloat4*)d_out);
}